// Round 1
// baseline (478.412 us; speedup 1.0000x reference)
//
#include <hip/hip_runtime.h>

#define N_NODES 100000
#define N_EDGES 1200000
#define D_IN 256
#define D_OUT 64

// ---------------------------------------------------------------------------
// Kernel 1: support = X @ W   [N_NODES, D_IN] @ [D_IN, D_OUT] -> [N_NODES, D_OUT]
// Wave-level: lane = output column (D_OUT == 64 == wavefront), each wave
// computes 16 rows. K-loop unrolled by 4. W row W[k][0..63] is a coalesced
// 256B load (L1/L2-resident after first touch); X values are wave-uniform
// broadcasts (float4).
// ---------------------------------------------------------------------------
__global__ __launch_bounds__(256) void gemm_xw(const float* __restrict__ X,
                                               const float* __restrict__ W,
                                               float* __restrict__ support,
                                               int n_rows) {
    const int lane = threadIdx.x & 63;
    const int wave = threadIdx.x >> 6;
    const int ROWS = 16;
    int row0 = (blockIdx.x * 4 + wave) * ROWS;
    if (row0 >= n_rows) return;

    float acc[ROWS];
#pragma unroll
    for (int r = 0; r < ROWS; ++r) acc[r] = 0.0f;

    const float* xbase = X + (size_t)row0 * D_IN;

    for (int k = 0; k < D_IN; k += 4) {
        float w0 = W[(k + 0) * D_OUT + lane];
        float w1 = W[(k + 1) * D_OUT + lane];
        float w2 = W[(k + 2) * D_OUT + lane];
        float w3 = W[(k + 3) * D_OUT + lane];
#pragma unroll
        for (int r = 0; r < ROWS; ++r) {
            float4 x = *reinterpret_cast<const float4*>(xbase + (size_t)r * D_IN + k);
            acc[r] = fmaf(x.x, w0, acc[r]);
            acc[r] = fmaf(x.y, w1, acc[r]);
            acc[r] = fmaf(x.z, w2, acc[r]);
            acc[r] = fmaf(x.w, w3, acc[r]);
        }
    }

#pragma unroll
    for (int r = 0; r < ROWS; ++r) {
        int row = row0 + r;
        if (row < n_rows) support[(size_t)row * D_OUT + lane] = acc[r];
    }
}

// ---------------------------------------------------------------------------
// Kernel 2: zero d_out (harness poisons it with 0xAA; we must start from 0
// every call since the scatter accumulates).
// ---------------------------------------------------------------------------
__global__ void zero_out(float4* __restrict__ out, int n4) {
    int i = blockIdx.x * blockDim.x + threadIdx.x;
    int stride = gridDim.x * blockDim.x;
    for (; i < n4; i += stride) out[i] = float4{0.0f, 0.0f, 0.0f, 0.0f};
}

// ---------------------------------------------------------------------------
// Kernel 3: COO scatter-add.  out[row] += val * support[col]  per edge.
// Each wave grabs a chunk of 64 edges (coalesced loads of rows/cols/vals),
// then iterates the 64 edges: broadcast edge via __shfl, lanes 0..63 handle
// the 64 output columns -> coalesced 256B gather + 64 consecutive-address
// f32 atomicAdds.
// ---------------------------------------------------------------------------
__global__ __launch_bounds__(256) void spmm_scatter(const int* __restrict__ rows,
                                                    const int* __restrict__ cols,
                                                    const float* __restrict__ vals,
                                                    const float* __restrict__ support,
                                                    float* __restrict__ out,
                                                    int n_edges) {
    const int lane = threadIdx.x & 63;
    const int wave_global = (int)((blockIdx.x * blockDim.x + threadIdx.x) >> 6);
    const int n_waves = (int)((gridDim.x * blockDim.x) >> 6);

    for (int base = wave_global * 64; base < n_edges; base += n_waves * 64) {
        int my_e = base + lane;  // N_EDGES is a multiple of 64 -> always valid
        int r = rows[my_e];
        int c = cols[my_e];
        float v = vals[my_e];

        int cnt = min(64, n_edges - base);
        for (int i = 0; i < cnt; ++i) {
            int row = __shfl(r, i);
            int col = __shfl(c, i);
            float val = __shfl(v, i);
            float s = support[(size_t)col * D_OUT + lane];
            atomicAdd(&out[(size_t)row * D_OUT + lane], val * s);
        }
    }
}

extern "C" void kernel_launch(void* const* d_in, const int* in_sizes, int n_in,
                              void* d_out, int out_size, void* d_ws, size_t ws_size,
                              hipStream_t stream) {
    const float* X      = (const float*)d_in[0];
    const float* W      = (const float*)d_in[1];
    const int*   A_rows = (const int*)d_in[2];
    const int*   A_cols = (const int*)d_in[3];
    const float* A_vals = (const float*)d_in[4];
    float* out = (float*)d_out;
    float* support = (float*)d_ws;  // 100000*64*4 = 25.6 MB scratch

    // Stage 1: support = X @ W
    {
        int rows_per_block = 4 * 16;  // 4 waves * 16 rows
        int nblocks = (N_NODES + rows_per_block - 1) / rows_per_block;
        gemm_xw<<<nblocks, 256, 0, stream>>>(X, W, support, N_NODES);
    }

    // Stage 2a: out = 0
    {
        int n4 = (N_NODES * D_OUT) / 4;
        zero_out<<<2048, 256, 0, stream>>>((float4*)out, n4);
    }

    // Stage 2b: out[row] += val * support[col] for each edge
    {
        int chunks = N_EDGES / 64;           // 18750 wave-chunks
        int nblocks = (chunks + 3) / 4;      // 4 waves per block
        spmm_scatter<<<nblocks, 256, 0, stream>>>(A_rows, A_cols, A_vals, support,
                                                  out, N_EDGES);
    }
}